// Round 4
// baseline (28.331 us; speedup 1.0000x reference)
//
#include <hip/hip_runtime.h>
#include <math.h>

// FRN projection head, MI355X — single fused kernel, R4: async-streamed loads.
// Math: hat = (StS+lam I)^-1 StS = I - lam*Minv ; B = rho*hat - I (symmetric)
//       G = B^2 ; neg_l2[img,n] = -(1/100) <G_n, C_img>,  C_img = A A^T (Gram)
// Minv via Gershgorin-bounded Chebyshev-1 init + 2 Newton-Schulz iterations.
// R4 layout (grid 305 x 256, 64KB LDS -> 2 blk/CU -> all co-resident):
//  - b 0..74   : support Grams, 2 imgs each (global_load_lds streamed) -> gflag
//  - b 75..79  : dedicated solve (spin 15 gflags, ILP sum, NS) -> G bf16, sflag
//  - b 80..304 : query, 2 imgs, 2 waves/img k-split, LDS reduce, dot, softmax
//  - b 80      : gathers 225 per-block loss partials (fixed order)

typedef __attribute__((ext_vector_type(8))) short short8;   // 8 x bf16 bits
typedef __attribute__((ext_vector_type(4))) float f32x4;

#define NSUP 150
#define NQ 450
#define PIX 100
#define IMG_STRIDE 6400   // 64*100 floats per image
#define MAGIC 0x5F3D2B1Cu

static __device__ __forceinline__ short bf16r(float x) {   // f32 -> bf16 (RNE)
  unsigned u = __builtin_bit_cast(unsigned, x);
  u += 0x7FFFu + ((u >> 16) & 1u);
  return (short)(u >> 16);
}
static __device__ __forceinline__ float b2f(short v) {
  return __builtin_bit_cast(float, ((unsigned)(unsigned short)v) << 16);
}
static __device__ __forceinline__ void st_flag(unsigned* p, unsigned v) {
  __threadfence();
  __hip_atomic_store(p, v, __ATOMIC_RELEASE, __HIP_MEMORY_SCOPE_AGENT);
}
static __device__ __forceinline__ void spin_flag(unsigned* p) {
  int guard = 1 << 22;
  while (__hip_atomic_load(p, __ATOMIC_ACQUIRE, __HIP_MEMORY_SCOPE_AGENT) != MAGIC
         && --guard) __builtin_amdgcn_s_sleep(2);
}

// async copy 1KB (64 lanes x 16B) global -> LDS. dst wave-uniform, src per-lane.
typedef const __attribute__((address_space(1))) void gas_void;
typedef __attribute__((address_space(3))) void las_void;
static __device__ __forceinline__ void gload1k(const float* src, float* dst, int lane) {
  __builtin_amdgcn_global_load_lds((gas_void*)(src + lane * 4), (las_void*)dst,
                                   16, 0, 0);
}

// one k-chunk (32 of 128, zero-padded past 100) of acc += A*A^T, A f32 in LDS.
// C/D layout: row = R*16 + (lane>>4)*4 + q, col = C*16 + (lane&15).
static __device__ __forceinline__ void gram_ks_lds(const float* img, f32x4 acc[4][4],
                                                   int ks, int r, int g) {
  short8 frag[4];
  const int kb = ks * 32 + g * 8;
  #pragma unroll
  for (int R = 0; R < 4; ++R) {
    short8 q;
    const float* p = img + (R * 16 + r) * PIX + kb;
    if (ks < 3) {
      float4 lo = *(const float4*)p;
      float4 hi = *(const float4*)(p + 4);
      q[0] = bf16r(lo.x); q[1] = bf16r(lo.y); q[2] = bf16r(lo.z); q[3] = bf16r(lo.w);
      q[4] = bf16r(hi.x); q[5] = bf16r(hi.y); q[6] = bf16r(hi.z); q[7] = bf16r(hi.w);
    } else if (g == 0) {                   // k = 96..99 valid, rest zero-pad
      float4 lo = *(const float4*)p;
      q[0] = bf16r(lo.x); q[1] = bf16r(lo.y); q[2] = bf16r(lo.z); q[3] = bf16r(lo.w);
      q[4] = 0; q[5] = 0; q[6] = 0; q[7] = 0;
    } else {
      #pragma unroll
      for (int j = 0; j < 8; ++j) q[j] = 0;
    }
    frag[R] = q;
  }
  #pragma unroll
  for (int R = 0; R < 4; ++R)
    #pragma unroll
    for (int C = 0; C < 4; ++C)
      acc[R][C] = __builtin_amdgcn_mfma_f32_16x16x32_bf16(frag[R], frag[C],
                                                          acc[R][C], 0, 0, 0);
}

// Quadrant (wr,wc) of D = A*B for 64x64 bf16 LDS matrices (stride 72).
// B must be SYMMETRIC (B-fragment gathered as rows of B).
static __device__ __forceinline__ void mm64q(const short* A, const short* B,
                                             f32x4 t[2][2], int r, int g,
                                             int wr, int wc) {
  #pragma unroll
  for (int ks = 0; ks < 2; ++ks) {
    short8 af[2], bfr[2];
    #pragma unroll
    for (int i = 0; i < 2; ++i) {
      af[i]  = *(const short8*)(A + (wr * 32 + i * 16 + r) * 72 + ks * 32 + g * 8);
      bfr[i] = *(const short8*)(B + (wc * 32 + i * 16 + r) * 72 + ks * 32 + g * 8);
    }
    #pragma unroll
    for (int i = 0; i < 2; ++i)
      #pragma unroll
      for (int j = 0; j < 2; ++j)
        t[i][j] = __builtin_amdgcn_mfma_f32_16x16x32_bf16(af[i], bfr[j],
                                                          t[i][j], 0, 0, 0);
  }
}

#define ZERO_ACC4(t)                                  \
  _Pragma("unroll") for (int R = 0; R < 4; ++R)       \
  _Pragma("unroll") for (int C = 0; C < 4; ++C)       \
  _Pragma("unroll") for (int q = 0; q < 4; ++q) t[R][C][q] = 0.f;

#define ZERO_ACC2(t)                                  \
  _Pragma("unroll") for (int R = 0; R < 2; ++R)       \
  _Pragma("unroll") for (int C = 0; C < 2; ++C)       \
  _Pragma("unroll") for (int q = 0; q < 4; ++q) t[R][C][q] = 0.f;

__global__ __launch_bounds__(256) void k_fused(
    const float* __restrict__ feat, const int* __restrict__ label,
    const float* __restrict__ scale, const float* __restrict__ rvec,
    float* __restrict__ out,
    float* __restrict__ partial,            // 75*4096 f32
    unsigned short* __restrict__ Gneg,      // 5*4096 bf16 (-B^2/100)
    float* __restrict__ blockloss,          // 225 f32
    unsigned* __restrict__ gflag,           // 75
    unsigned* __restrict__ sflag,           // 5
    unsigned* __restrict__ lflag) {         // 225
  __shared__ __align__(16) char smem[65536];
  const int b = blockIdx.x, tid = threadIdx.x;
  const int wave = tid >> 6, lane = tid & 63;
  const int r = lane & 15, g = lane >> 4;

  if (b < 75) {
    // ============ support-Gram partial: class b/15, imgs (b%15)*2 .. +1 ======
    float* img0 = (float*)smem;             // [0, 25600)
    float* img1 = (float*)(smem + 25600);   // [25600, 51200)
    float (*gbuf)[4096] = (float (*)[4096])smem;   // reused post-barrier
    const int cls = b / 15, grp = b % 15;
    const float* f0 = feat + (size_t)(cls * 30 + grp * 2) * IMG_STRIDE;
    const float* f1 = f0 + IMG_STRIDE;

    {  // stream 50 x 1KB chunks, split 13/13/12/12 across waves
      const int beg = (wave < 2) ? wave * 13 : 26 + (wave - 2) * 12;
      const int cnt = (wave < 2) ? 13 : 12;
      for (int i = 0; i < cnt; ++i) {
        const int ch = beg + i;
        const float* src = (ch < 25) ? f0 + ch * 256 : f1 + (ch - 25) * 256;
        float* dst = (ch < 25) ? img0 + ch * 256 : img1 + (ch - 25) * 256;
        gload1k(src, dst, lane);
      }
    }
    asm volatile("s_waitcnt vmcnt(0)" ::: "memory");
    __syncthreads();

    f32x4 acc[4][4];
    ZERO_ACC4(acc)
    gram_ks_lds(img0, acc, wave, r, g);     // wave w owns k-chunk w
    gram_ks_lds(img1, acc, wave, r, g);
    __syncthreads();                        // images dead; gbuf takes over

    #pragma unroll
    for (int R = 0; R < 4; ++R)
      #pragma unroll
      for (int C = 0; C < 4; ++C)
        #pragma unroll
        for (int q = 0; q < 4; ++q) {
          const int row = R * 16 + g * 4 + q, col = C * 16 + r;
          gbuf[wave][row * 64 + col] = acc[R][C][q];
        }
    __syncthreads();

    float* outp = partial + (size_t)b * 4096;
    for (int c = tid; c < 1024; c += 256) {
      f32x4 s0 = *(const f32x4*)&gbuf[0][4 * c];
      f32x4 s1 = *(const f32x4*)&gbuf[1][4 * c];
      f32x4 s2 = *(const f32x4*)&gbuf[2][4 * c];
      f32x4 s3 = *(const f32x4*)&gbuf[3][4 * c];
      f32x4 s = s0 + s1 + s2 + s3;
      *(float4*)(outp + 4 * c) = *(float4*)&s;
    }
    __syncthreads();
    if (tid == 0) st_flag(&gflag[b], MAGIC);
    return;
  }

  if (b < 80) {
    // ======================= per-class solve (class n) ======================
    float* Ms   = (float*)(smem);            // 64*65 f32
    short* Mb   = (short*)(smem + 16640);    // 64*72 bf16
    short* Tb   = (short*)(smem + 25856);
    short* Xa   = (short*)(smem + 35072);
    short* Xc   = (short*)(smem + 44288);
    float* radp = (float*)(smem + 53504);    // [4][64]
    float* scal = (float*)(smem + 54528);    // sS, sTheta

    const int n = b - 75;
    const int wr = wave >> 1, wc = wave & 1;
    const float lam = 46.875f * expf(rvec[0]);   // reg = 3000/64
    const float rho = expf(rvec[1]);

    if (tid < 15) spin_flag(&gflag[n * 15 + tid]);
    __syncthreads();

    {  // M = (1/64) * sum of 15 partials (deep-ILP coalesced) + lam on diag
      const float* base = partial + (size_t)n * 15 * 4096;
      for (int c = tid; c < 1024; c += 256) {
        float4 s = {0.f, 0.f, 0.f, 0.f};
        #pragma unroll
        for (int p = 0; p < 15; ++p) {
          float4 v = *(const float4*)(base + p * 4096 + 4 * c);
          s.x += v.x; s.y += v.y; s.z += v.z; s.w += v.w;
        }
        const int e = 4 * c, row = e >> 6, col = e & 63;
        Ms[row * 65 + col + 0] = s.x * (1.f / 64.f);
        Ms[row * 65 + col + 1] = s.y * (1.f / 64.f);
        Ms[row * 65 + col + 2] = s.z * (1.f / 64.f);
        Ms[row * 65 + col + 3] = s.w * (1.f / 64.f);
      }
    }
    __syncthreads();
    if (tid < 64) Ms[tid * 65 + tid] += lam;
    __syncthreads();

    {  // Gershgorin (4 threads/row) -> Chebyshev-1 init params
      const int row = tid & 63, part = tid >> 6;
      float s = 0.f;
      #pragma unroll
      for (int k = 0; k < 16; ++k) s += fabsf(Ms[row * 65 + part * 16 + k]);
      radp[part * 64 + row] = s;
    }
    __syncthreads();
    if (tid < 64) {
      const float diag = Ms[tid * 65 + tid];
      const float rad = radp[tid] + radp[64 + tid] + radp[128 + tid] +
                        radp[192 + tid] - fabsf(diag);
      float lo = diag - rad, hi = diag + rad;
      for (int off = 32; off; off >>= 1) {
        lo = fminf(lo, __shfl_down(lo, off));
        hi = fmaxf(hi, __shfl_down(hi, off));
      }
      if (tid == 0) {
        const float a = fmaxf(lo, lam);   // spectrum >= lam (StS is PSD)
        const float bb = hi;
        const float s = a + bb, d = bb - a;
        scal[0] = s;
        scal[1] = 8.f / (2.f * s * s - d * d);   // X0 = theta*(s*I - M)
      }
    }
    __syncthreads();
    const float s0 = scal[0], theta = scal[1];

    for (int e = tid; e < 4096; e += 256) {      // Mb, X0
      const int i = e >> 6, j = e & 63;
      const float m = Ms[i * 65 + j];
      Mb[i * 72 + j] = bf16r(m);
      Xa[i * 72 + j] = bf16r(theta * (((i == j) ? s0 : 0.f) - m));
    }
    __syncthreads();

    short* x = Xa;                               // 2 Newton-Schulz iterations
    short* xn = Xc;
    for (int it = 0; it < 2; ++it) {
      {
        f32x4 t[2][2];
        ZERO_ACC2(t)
        mm64q(x, Mb, t, r, g, wr, wc);           // T = X*M (M symmetric)
        #pragma unroll
        for (int i = 0; i < 2; ++i)
          #pragma unroll
          for (int j = 0; j < 2; ++j)
            #pragma unroll
            for (int q = 0; q < 4; ++q) {
              const int row = wr * 32 + i * 16 + g * 4 + q;
              const int col = wc * 32 + j * 16 + r;
              Tb[row * 72 + col] = bf16r(t[i][j][q]);
            }
      }
      __syncthreads();
      {
        f32x4 t[2][2];
        ZERO_ACC2(t)
        mm64q(Tb, x, t, r, g, wr, wc);           // T*X (X ~symmetric)
        #pragma unroll
        for (int i = 0; i < 2; ++i)
          #pragma unroll
          for (int j = 0; j < 2; ++j)
            #pragma unroll
            for (int q = 0; q < 4; ++q) {
              const int row = wr * 32 + i * 16 + g * 4 + q;
              const int col = wc * 32 + j * 16 + r;
              const int idx = row * 72 + col;
              xn[idx] = bf16r(2.f * b2f(x[idx]) - t[i][j][q]);
            }
      }
      __syncthreads();
      short* tmp = x; x = xn; xn = tmp;
    }

    for (int e = tid; e < 4096; e += 256) {      // B = (rho-1)I - rho*lam*X
      const int i = e >> 6, j = e & 63;
      const float xv = b2f(x[i * 72 + j]);
      Tb[i * 72 + j] = bf16r(((i == j) ? (rho - 1.f) : 0.f) - rho * lam * xv);
    }
    __syncthreads();

    {  // G = B*B ; store bf16(-G/100)
      f32x4 t[2][2];
      ZERO_ACC2(t)
      mm64q(Tb, Tb, t, r, g, wr, wc);
      #pragma unroll
      for (int i = 0; i < 2; ++i)
        #pragma unroll
        for (int j = 0; j < 2; ++j)
          #pragma unroll
          for (int q = 0; q < 4; ++q) {
            const int row = wr * 32 + i * 16 + g * 4 + q;
            const int col = wc * 32 + j * 16 + r;
            Gneg[n * 4096 + row * 64 + col] =
                (unsigned short)bf16r(t[i][j][q] * (-0.01f));
          }
    }
    __syncthreads();
    if (tid == 0) st_flag(&sflag[n], MAGIC);
    return;
  }

  // ============== query: 2 imgs/block, 2 waves per img (k-split) ============
  const int qb = b - 80;                  // 0..224
  float* imgA = (float*)smem;             // [0, 25600)
  float* imgB = (float*)(smem + 25600);   // [25600, 51200)
  const int half = wave >> 1;             // img index within block
  const int gimg = qb * 2 + half;         // global query image 0..449
  const float* fq = feat + (size_t)(NSUP + gimg) * IMG_STRIDE;
  float* mybuf = half ? imgB : imgA;

  {  // waves 0,1 stage imgA; waves 2,3 stage imgB (13/12 chunks)
    const int w2 = wave & 1;
    const int beg = w2 ? 13 : 0;
    const int cnt = w2 ? 12 : 13;
    for (int i = 0; i < cnt; ++i)
      gload1k(fq + (beg + i) * 256, mybuf + (beg + i) * 256, lane);
  }
  asm volatile("s_waitcnt vmcnt(0)" ::: "memory");
  __syncthreads();

  f32x4 acc[4][4];
  ZERO_ACC4(acc)
  const int kbase = (wave & 1) * 2;       // wave even: ks 0,1 ; odd: ks 2,3
  gram_ks_lds(mybuf, acc, kbase, r, g);
  gram_ks_lds(mybuf, acc, kbase + 1, r, g);
  __syncthreads();                        // all MFMAs done; img bufs dead

  float* p1 = (float*)(smem + 32768);     // wave1 partial (16KB)
  float* p3 = (float*)(smem + 49152);     // wave3 partial (16KB)
  if (wave & 1) {
    float* dst = (wave == 1) ? p1 : p3;
    #pragma unroll
    for (int R = 0; R < 4; ++R)
      #pragma unroll
      for (int C = 0; C < 4; ++C)
        #pragma unroll
        for (int q = 0; q < 4; ++q) {
          const int row = R * 16 + g * 4 + q, col = C * 16 + r;
          dst[row * 64 + col] = acc[R][C][q];
        }
  }
  __syncthreads();
  if (!(wave & 1)) {
    const float* src = (wave == 0) ? p1 : p3;
    #pragma unroll
    for (int R = 0; R < 4; ++R)
      #pragma unroll
      for (int C = 0; C < 4; ++C)
        #pragma unroll
        for (int q = 0; q < 4; ++q) {
          const int row = R * 16 + g * 4 + q, col = C * 16 + r;
          acc[R][C][q] += src[row * 64 + col];
        }
  }

  if (tid < 5) spin_flag(&sflag[tid]);
  __syncthreads();                        // p1/p3 reads done before this

  // stage G bf16 into LDS, row stride 72 (16B-aligned short8 copies)
  unsigned short* Gs = (unsigned short*)smem;   // 5*64*72*2 = 46080 B
  for (int e = tid; e < 2560; e += 256) {
    const int nn = e >> 9, rem = e & 511, row = rem >> 3, c8 = (rem & 7) << 3;
    *(short8*)&Gs[nn * 4608 + row * 72 + c8] =
        *(const short8*)&Gneg[nn * 4096 + row * 64 + c8];
  }
  __syncthreads();

  float* wl = (float*)(smem + 46080);     // 2 floats (loss img A, B)
  if (!(wave & 1)) {
    float nl[5] = {0.f, 0.f, 0.f, 0.f, 0.f};
    #pragma unroll
    for (int R = 0; R < 4; ++R)
      #pragma unroll
      for (int C = 0; C < 4; ++C)
        #pragma unroll
        for (int q = 0; q < 4; ++q) {
          const int row = R * 16 + g * 4 + q, col = C * 16 + r;
          const float cv = acc[R][C][q] * (1.f / 64.f);
          const int idx = row * 72 + col;
          #pragma unroll
          for (int nn = 0; nn < 5; ++nn)
            nl[nn] += b2f((short)Gs[nn * 4608 + idx]) * cv;
        }
    #pragma unroll
    for (int nn = 0; nn < 5; ++nn)
      for (int off = 32; off; off >>= 1) nl[nn] += __shfl_down(nl[nn], off);

    if (lane == 0) {
      float mx = nl[0];
      #pragma unroll
      for (int nn = 1; nn < 5; ++nn) mx = fmaxf(mx, nl[nn]);
      float ex[5], se = 0.f;
      #pragma unroll
      for (int nn = 0; nn < 5; ++nn) { ex[nn] = expf(nl[nn] - mx); se += ex[nn]; }
      const float inv = 1.f / se;
      #pragma unroll
      for (int nn = 0; nn < 5; ++nn) out[gimg * 5 + nn] = ex[nn] * inv;

      const float sc = scale[0];
      float mx2 = nl[0] * sc;
      #pragma unroll
      for (int nn = 1; nn < 5; ++nn) mx2 = fmaxf(mx2, nl[nn] * sc);
      float se2 = 0.f;
      #pragma unroll
      for (int nn = 0; nn < 5; ++nn) se2 += expf(nl[nn] * sc - mx2);
      wl[half] = mx2 + logf(se2) - nl[label[gimg]] * sc;   // -log p[label]
    }
  }
  __syncthreads();
  if (tid == 0) {
    blockloss[qb] = wl[0] + wl[1];
    st_flag(&lflag[qb], MAGIC);
  }

  if (qb == 0 && wave == 0) {             // final loss gather (block 80)
    for (int i = lane; i < 225; i += 64) spin_flag(&lflag[i]);
    float s = 0.f;
    for (int i = lane; i < 225; i += 64) s += blockloss[i];
    for (int off = 32; off; off >>= 1) s += __shfl_down(s, off);
    if (lane == 0) out[2250] = s / 450.f;
  }
}

extern "C" void kernel_launch(void* const* d_in, const int* in_sizes, int n_in,
                              void* d_out, int out_size, void* d_ws, size_t ws_size,
                              hipStream_t stream) {
  const float* feat  = (const float*)d_in[0];
  const int*   label = (const int*)d_in[1];
  const float* scale = (const float*)d_in[2];
  const float* rvec  = (const float*)d_in[3];
  float* out = (float*)d_out;

  char* ws = (char*)d_ws;
  float*          partial   = (float*)ws;                       // 1,228,800 B
  unsigned short* Gneg      = (unsigned short*)(ws + 1228800);  //    40,960 B
  float*          blockloss = (float*)(ws + 1269760);           //       900 B
  unsigned*       flags     = (unsigned*)(ws + 1270784);
  unsigned* gflag = flags;          // 75
  unsigned* sflag = flags + 80;     // 5
  unsigned* lflag = flags + 96;     // 225

  k_fused<<<dim3(305), dim3(256), 0, stream>>>(feat, label, scale, rvec, out,
                                               partial, Gneg, blockloss,
                                               gflag, sflag, lflag);
}

// Round 5
// 24.398 us; speedup vs baseline: 1.1612x; 1.1612x over previous
//
#include <hip/hip_runtime.h>
#include <math.h>

// FRN projection head, MI355X — single fused kernel.
// Math: hat = (StS+lam I)^-1 StS = I - lam*Minv ; B = rho*hat - I (symmetric)
//       G = B^2 ; neg_l2[img,n] = -(1/100) <G_n, C_img>,  C_img = A A^T (Gram)
// Minv via Gershgorin-bounded Chebyshev-1 init + 2 Newton-Schulz iterations.
// R5 = R3 structure + lightweight sync: RELAXED spin-polls (no per-poll L2
// invalidate) + single acquire fence per consumer; release fence + relaxed
// store per producer. Standard C++ fence-fence synchronizes-with pattern.
//  - blocks 0..29 : support-Gram partials (5 imgs, 4-wave k-split) -> gflag
//  - blocks 0..4  : + per-class solve (quadrant NS on 4 waves) -> G bf16, sflag
//  - blocks 30..142: query Grams in regs (overlap solve), wait, dot, softmax
//  - block 30     : gathers 113 per-block loss partials (fixed order)
// Grid 143 blocks x 64KB LDS -> 2 blocks/CU -> all co-resident: no deadlock.

typedef __attribute__((ext_vector_type(8))) short short8;   // 8 x bf16 bits
typedef __attribute__((ext_vector_type(4))) short short4v;  // 4 x bf16 bits
typedef __attribute__((ext_vector_type(4))) float f32x4;

#define NSUP 150
#define NQ 450
#define PIX 100
#define IMG_STRIDE 6400   // 64*100 floats per image
#define MAGIC 0x5F3D2B1Cu

static __device__ __forceinline__ short bf16r(float x) {   // f32 -> bf16 (RNE)
  unsigned u = __builtin_bit_cast(unsigned, x);
  u += 0x7FFFu + ((u >> 16) & 1u);
  return (short)(u >> 16);
}
static __device__ __forceinline__ float b2f(short v) {
  return __builtin_bit_cast(float, ((unsigned)(unsigned short)v) << 16);
}
// producer: one agent release fence (writeback), then relaxed flag store.
static __device__ __forceinline__ void st_flag(unsigned* p, unsigned v) {
  __builtin_amdgcn_fence(__ATOMIC_RELEASE, "agent");
  __hip_atomic_store(p, v, __ATOMIC_RELAXED, __HIP_MEMORY_SCOPE_AGENT);
}
// consumer: relaxed poll — NO per-iteration cache invalidate. Caller must
// issue __builtin_amdgcn_fence(__ATOMIC_ACQUIRE, "agent") once after.
static __device__ __forceinline__ void spin_rlx(unsigned* p) {
  int guard = 1 << 22;
  while (__hip_atomic_load(p, __ATOMIC_RELAXED, __HIP_MEMORY_SCOPE_AGENT) != MAGIC
         && --guard) __builtin_amdgcn_s_sleep(2);
}

// Accumulate acc += A*A^T for one image (A = 64x100 f32, k padded to 128).
// C/D layout: row = R*16 + (lane>>4)*4 + q, col = C*16 + (lane&15).
static __device__ __forceinline__ void gram_accum(const float* __restrict__ f,
                                                  f32x4 acc[4][4], int r, int g) {
  #pragma unroll
  for (int ks = 0; ks < 4; ++ks) {
    short8 frag[4];
    const int kb = ks * 32 + g * 8;
    #pragma unroll
    for (int R = 0; R < 4; ++R) {
      short8 q;
      const float* p = f + (R * 16 + r) * PIX + kb;
      if (ks < 3) {
        float4 lo = *(const float4*)p;
        float4 hi = *(const float4*)(p + 4);
        q[0] = bf16r(lo.x); q[1] = bf16r(lo.y); q[2] = bf16r(lo.z); q[3] = bf16r(lo.w);
        q[4] = bf16r(hi.x); q[5] = bf16r(hi.y); q[6] = bf16r(hi.z); q[7] = bf16r(hi.w);
      } else if (g == 0) {                 // k = 96..99 valid, rest zero-pad
        float4 lo = *(const float4*)p;
        q[0] = bf16r(lo.x); q[1] = bf16r(lo.y); q[2] = bf16r(lo.z); q[3] = bf16r(lo.w);
        q[4] = 0; q[5] = 0; q[6] = 0; q[7] = 0;
      } else {
        #pragma unroll
        for (int j = 0; j < 8; ++j) q[j] = 0;
      }
      frag[R] = q;
    }
    #pragma unroll
    for (int R = 0; R < 4; ++R)
      #pragma unroll
      for (int C = 0; C < 4; ++C)
        acc[R][C] = __builtin_amdgcn_mfma_f32_16x16x32_bf16(frag[R], frag[C],
                                                            acc[R][C], 0, 0, 0);
  }
}

// Quadrant (wr,wc) of D = A*B for 64x64 bf16 LDS matrices (stride 72).
// B must be SYMMETRIC (B-fragment gathered as rows of B).
static __device__ __forceinline__ void mm64q(const short* A, const short* B,
                                             f32x4 t[2][2], int r, int g,
                                             int wr, int wc) {
  #pragma unroll
  for (int ks = 0; ks < 2; ++ks) {
    short8 af[2], bfr[2];
    #pragma unroll
    for (int i = 0; i < 2; ++i) {
      af[i]  = *(const short8*)(A + (wr * 32 + i * 16 + r) * 72 + ks * 32 + g * 8);
      bfr[i] = *(const short8*)(B + (wc * 32 + i * 16 + r) * 72 + ks * 32 + g * 8);
    }
    #pragma unroll
    for (int i = 0; i < 2; ++i)
      #pragma unroll
      for (int j = 0; j < 2; ++j)
        t[i][j] = __builtin_amdgcn_mfma_f32_16x16x32_bf16(af[i], bfr[j],
                                                          t[i][j], 0, 0, 0);
  }
}

#define ZERO_ACC4(t)                                  \
  _Pragma("unroll") for (int R = 0; R < 4; ++R)       \
  _Pragma("unroll") for (int C = 0; C < 4; ++C)       \
  _Pragma("unroll") for (int q = 0; q < 4; ++q) t[R][C][q] = 0.f;

#define ZERO_ACC2(t)                                  \
  _Pragma("unroll") for (int R = 0; R < 2; ++R)       \
  _Pragma("unroll") for (int C = 0; C < 2; ++C)       \
  _Pragma("unroll") for (int q = 0; q < 4; ++q) t[R][C][q] = 0.f;

__global__ __launch_bounds__(256) void k_fused(
    const float* __restrict__ feat, const int* __restrict__ label,
    const float* __restrict__ scale, const float* __restrict__ rvec,
    float* __restrict__ out,
    float* __restrict__ partial,            // 30*4096 f32
    unsigned short* __restrict__ Gneg,      // 5*4096 bf16 (-B^2/100)
    float* __restrict__ blockloss,          // 113 f32
    unsigned* __restrict__ gflag,           // 30
    unsigned* __restrict__ sflag,           // 5
    unsigned* __restrict__ lflag) {         // 113
  __shared__ __align__(16) char smem[65536];
  const int b = blockIdx.x, tid = threadIdx.x;
  const int wave = tid >> 6, lane = tid & 63;
  const int r = lane & 15, g = lane >> 4;

  if (b < 30) {
    // ================= support-Gram partial (class b/6, group b%6) ==========
    float (*gbuf)[4096] = (float (*)[4096])smem;
    const int cls = b / 6, jb = b % 6;
    const int ks = wave, kb = ks * 32 + g * 8;
    f32x4 acc[4][4];
    ZERO_ACC4(acc)
    for (int im = 0; im < 5; ++im) {
      const float* f = feat + (size_t)(cls * 30 + jb * 5 + im) * IMG_STRIDE;
      short8 frag[4];
      #pragma unroll
      for (int R = 0; R < 4; ++R) {
        short8 q;
        const float* p = f + (R * 16 + r) * PIX + kb;
        if (ks < 3) {
          float4 lo = *(const float4*)p;
          float4 hi = *(const float4*)(p + 4);
          q[0] = bf16r(lo.x); q[1] = bf16r(lo.y); q[2] = bf16r(lo.z); q[3] = bf16r(lo.w);
          q[4] = bf16r(hi.x); q[5] = bf16r(hi.y); q[6] = bf16r(hi.z); q[7] = bf16r(hi.w);
        } else if (g == 0) {
          float4 lo = *(const float4*)p;
          q[0] = bf16r(lo.x); q[1] = bf16r(lo.y); q[2] = bf16r(lo.z); q[3] = bf16r(lo.w);
          q[4] = 0; q[5] = 0; q[6] = 0; q[7] = 0;
        } else {
          #pragma unroll
          for (int j = 0; j < 8; ++j) q[j] = 0;
        }
        frag[R] = q;
      }
      #pragma unroll
      for (int R = 0; R < 4; ++R)
        #pragma unroll
        for (int C = 0; C < 4; ++C)
          acc[R][C] = __builtin_amdgcn_mfma_f32_16x16x32_bf16(frag[R], frag[C],
                                                              acc[R][C], 0, 0, 0);
    }
    #pragma unroll
    for (int R = 0; R < 4; ++R)
      #pragma unroll
      for (int C = 0; C < 4; ++C)
        #pragma unroll
        for (int q = 0; q < 4; ++q) {
          const int row = R * 16 + g * 4 + q, col = C * 16 + r;
          gbuf[wave][row * 64 + col] = acc[R][C][q];
        }
    __syncthreads();
    float* outp = partial + (size_t)b * 4096;
    for (int c = tid; c < 1024; c += 256) {
      f32x4 s0 = *(const f32x4*)&gbuf[0][4 * c];
      f32x4 s1 = *(const f32x4*)&gbuf[1][4 * c];
      f32x4 s2 = *(const f32x4*)&gbuf[2][4 * c];
      f32x4 s3 = *(const f32x4*)&gbuf[3][4 * c];
      f32x4 s = s0 + s1 + s2 + s3;
      *(float4*)(outp + 4 * c) = *(float4*)&s;
    }
    __syncthreads();                         // gbuf dead; smem reused below
    if (tid == 0) st_flag(&gflag[b], MAGIC);
    if (b >= 5) return;

    // ======================= per-class solve (class n = b) ==================
    float* Ms   = (float*)(smem);            // 64*65 f32
    short* Mb   = (short*)(smem + 16640);    // 64*72 bf16
    short* Tb   = (short*)(smem + 25856);
    short* Xa   = (short*)(smem + 35072);
    short* Xc   = (short*)(smem + 44288);
    float* radp = (float*)(smem + 53504);    // [4][64]
    float* scal = (float*)(smem + 54528);    // sS, sTheta

    const int n = b;
    const int wr = wave >> 1, wc = wave & 1;
    const float lam = 46.875f * expf(rvec[0]);   // reg = 3000/64
    const float rho = expf(rvec[1]);

    if (tid < 6) spin_rlx(&gflag[6 * n + tid]);
    __syncthreads();
    __builtin_amdgcn_fence(__ATOMIC_ACQUIRE, "agent");   // one inv per wave

    {  // M = (1/64) * sum of 6 partials (+ lam on diag)
      const float* base = partial + (size_t)n * 6 * 4096;
      for (int c = tid; c < 1024; c += 256) {
        float4 s = {0.f, 0.f, 0.f, 0.f};
        #pragma unroll
        for (int p = 0; p < 6; ++p) {
          float4 v = *(const float4*)(base + p * 4096 + 4 * c);
          s.x += v.x; s.y += v.y; s.z += v.z; s.w += v.w;
        }
        const int e = 4 * c, row = e >> 6, col = e & 63;
        Ms[row * 65 + col + 0] = s.x * (1.f / 64.f);
        Ms[row * 65 + col + 1] = s.y * (1.f / 64.f);
        Ms[row * 65 + col + 2] = s.z * (1.f / 64.f);
        Ms[row * 65 + col + 3] = s.w * (1.f / 64.f);
      }
    }
    __syncthreads();
    if (tid < 64) Ms[tid * 65 + tid] += lam;
    __syncthreads();

    {  // Gershgorin (4 threads/row) -> Chebyshev-1 init params
      const int row = tid & 63, part = tid >> 6;
      float s = 0.f;
      #pragma unroll
      for (int k = 0; k < 16; ++k) s += fabsf(Ms[row * 65 + part * 16 + k]);
      radp[part * 64 + row] = s;
    }
    __syncthreads();
    if (tid < 64) {
      const float diag = Ms[tid * 65 + tid];
      const float rad = radp[tid] + radp[64 + tid] + radp[128 + tid] +
                        radp[192 + tid] - fabsf(diag);
      float lo = diag - rad, hi = diag + rad;
      for (int off = 32; off; off >>= 1) {
        lo = fminf(lo, __shfl_down(lo, off));
        hi = fmaxf(hi, __shfl_down(hi, off));
      }
      if (tid == 0) {
        const float a = fmaxf(lo, lam);   // spectrum >= lam (StS is PSD)
        const float bb = hi;
        const float s = a + bb, d = bb - a;
        scal[0] = s;
        scal[1] = 8.f / (2.f * s * s - d * d);   // X0 = theta*(s*I - M)
      }
    }
    __syncthreads();
    const float s0 = scal[0], theta = scal[1];

    for (int e = tid; e < 4096; e += 256) {      // Mb, X0
      const int i = e >> 6, j = e & 63;
      const float m = Ms[i * 65 + j];
      Mb[i * 72 + j] = bf16r(m);
      Xa[i * 72 + j] = bf16r(theta * (((i == j) ? s0 : 0.f) - m));
    }
    __syncthreads();

    short* x = Xa;                               // 2 Newton-Schulz iterations
    short* xn = Xc;
    for (int it = 0; it < 2; ++it) {
      {
        f32x4 t[2][2];
        ZERO_ACC2(t)
        mm64q(x, Mb, t, r, g, wr, wc);           // T = X*M (M symmetric)
        #pragma unroll
        for (int i = 0; i < 2; ++i)
          #pragma unroll
          for (int j = 0; j < 2; ++j)
            #pragma unroll
            for (int q = 0; q < 4; ++q) {
              const int row = wr * 32 + i * 16 + g * 4 + q;
              const int col = wc * 32 + j * 16 + r;
              Tb[row * 72 + col] = bf16r(t[i][j][q]);
            }
      }
      __syncthreads();
      {
        f32x4 t[2][2];
        ZERO_ACC2(t)
        mm64q(Tb, x, t, r, g, wr, wc);           // T*X (X ~symmetric)
        #pragma unroll
        for (int i = 0; i < 2; ++i)
          #pragma unroll
          for (int j = 0; j < 2; ++j)
            #pragma unroll
            for (int q = 0; q < 4; ++q) {
              const int row = wr * 32 + i * 16 + g * 4 + q;
              const int col = wc * 32 + j * 16 + r;
              const int idx = row * 72 + col;
              xn[idx] = bf16r(2.f * b2f(x[idx]) - t[i][j][q]);
            }
      }
      __syncthreads();
      short* tmp = x; x = xn; xn = tmp;
    }

    for (int e = tid; e < 4096; e += 256) {      // B = (rho-1)I - rho*lam*X
      const int i = e >> 6, j = e & 63;
      const float xv = b2f(x[i * 72 + j]);
      Tb[i * 72 + j] = bf16r(((i == j) ? (rho - 1.f) : 0.f) - rho * lam * xv);
    }
    __syncthreads();

    {  // G = B*B ; store bf16(-G/100)
      f32x4 t[2][2];
      ZERO_ACC2(t)
      mm64q(Tb, Tb, t, r, g, wr, wc);
      #pragma unroll
      for (int i = 0; i < 2; ++i)
        #pragma unroll
        for (int j = 0; j < 2; ++j)
          #pragma unroll
          for (int q = 0; q < 4; ++q) {
            const int row = wr * 32 + i * 16 + g * 4 + q;
            const int col = wc * 32 + j * 16 + r;
            Gneg[n * 4096 + row * 64 + col] =
                (unsigned short)bf16r(t[i][j][q] * (-0.01f));
          }
    }
    __syncthreads();
    if (tid == 0) st_flag(&sflag[n], MAGIC);
    return;
  }

  // ======================= query dist + softmax + loss ======================
  const int img = (b - 30) * 4 + wave;
  const bool ok = img < NQ;
  f32x4 acc[4][4];
  ZERO_ACC4(acc)
  if (ok)                                       // overlaps the solve
    gram_accum(feat + (size_t)(NSUP + img) * IMG_STRIDE, acc, r, g);

  if (tid < 5) spin_rlx(&sflag[tid]);
  __syncthreads();
  __builtin_amdgcn_fence(__ATOMIC_ACQUIRE, "agent");   // one inv per wave

  // stage G (bf16) into LDS, row stride 68 (bank-spread, 8B aligned writes)
  unsigned short* Gs = (unsigned short*)smem;   // 5*64*68 ushorts = 43520 B
  for (int e = tid; e < 5120; e += 256) {
    const int e4 = e * 4;
    const int nn = e4 >> 12, rem = e4 & 4095, row = rem >> 6, col = rem & 63;
    *(short4v*)&Gs[nn * 4352 + row * 68 + col] = *(const short4v*)&Gneg[e4];
  }
  __syncthreads();

  float myloss = 0.f;
  float nl[5] = {0.f, 0.f, 0.f, 0.f, 0.f};
  if (ok) {
    #pragma unroll
    for (int R = 0; R < 4; ++R)
      #pragma unroll
      for (int C = 0; C < 4; ++C)
        #pragma unroll
        for (int q = 0; q < 4; ++q) {
          const int row = R * 16 + g * 4 + q, col = C * 16 + r;
          const float cv = acc[R][C][q] * (1.f / 64.f);
          const int idx = row * 68 + col;
          #pragma unroll
          for (int nn = 0; nn < 5; ++nn)
            nl[nn] += b2f((short)Gs[nn * 4352 + idx]) * cv;
        }
    #pragma unroll
    for (int nn = 0; nn < 5; ++nn)
      for (int off = 32; off; off >>= 1) nl[nn] += __shfl_down(nl[nn], off);

    if (lane == 0) {
      float mx = nl[0];
      #pragma unroll
      for (int nn = 1; nn < 5; ++nn) mx = fmaxf(mx, nl[nn]);
      float ex[5], se = 0.f;
      #pragma unroll
      for (int nn = 0; nn < 5; ++nn) { ex[nn] = expf(nl[nn] - mx); se += ex[nn]; }
      const float inv = 1.f / se;
      #pragma unroll
      for (int nn = 0; nn < 5; ++nn) out[img * 5 + nn] = ex[nn] * inv;

      const float sc = scale[0];
      float mx2 = nl[0] * sc;
      #pragma unroll
      for (int nn = 1; nn < 5; ++nn) mx2 = fmaxf(mx2, nl[nn] * sc);
      float se2 = 0.f;
      #pragma unroll
      for (int nn = 0; nn < 5; ++nn) se2 += expf(nl[nn] * sc - mx2);
      myloss = mx2 + logf(se2) - nl[label[img]] * sc;   // -log p[label]
    }
  }

  float* wl = (float*)(smem + 43584);
  if (lane == 0) wl[wave] = ok ? myloss : 0.f;
  __syncthreads();
  if (tid == 0) {
    blockloss[b - 30] = wl[0] + wl[1] + wl[2] + wl[3];
    st_flag(&lflag[b - 30], MAGIC);
  }

  if (b == 30 && wave == 0) {                   // final loss gather, block 30
    for (int i = lane; i < 113; i += 64) spin_rlx(&lflag[i]);
    __builtin_amdgcn_fence(__ATOMIC_ACQUIRE, "agent");
    float s = 0.f;
    for (int i = lane; i < 113; i += 64) s += blockloss[i];
    for (int off = 32; off; off >>= 1) s += __shfl_down(s, off);
    if (lane == 0) out[2250] = s / 450.f;
  }
}

extern "C" void kernel_launch(void* const* d_in, const int* in_sizes, int n_in,
                              void* d_out, int out_size, void* d_ws, size_t ws_size,
                              hipStream_t stream) {
  const float* feat  = (const float*)d_in[0];
  const int*   label = (const int*)d_in[1];
  const float* scale = (const float*)d_in[2];
  const float* rvec  = (const float*)d_in[3];
  float* out = (float*)d_out;

  char* ws = (char*)d_ws;
  float*          partial   = (float*)ws;                  //      0 .. 491520
  unsigned short* Gneg      = (unsigned short*)(ws + 491520);   // 40960 B
  float*          blockloss = (float*)(ws + 532480);       //   452 B
  unsigned*       flags     = (unsigned*)(ws + 532992);
  unsigned* gflag = flags;         // 30
  unsigned* sflag = flags + 32;    // 5
  unsigned* lflag = flags + 64;    // 113

  k_fused<<<dim3(143), dim3(256), 0, stream>>>(feat, label, scale, rvec, out,
                                               partial, Gneg, blockloss,
                                               gflag, sflag, lflag);
}